// Round 7
// baseline (145.937 us; speedup 1.0000x reference)
//
#include <hip/hip_runtime.h>
#include <hip/hip_bf16.h>
#include <stdint.h>

typedef __bf16 bf16x8 __attribute__((ext_vector_type(8)));
typedef float  f32x16 __attribute__((ext_vector_type(16)));

// ---------- helpers ----------

__device__ __forceinline__ uint32_t rn2_bf16(uint32_t lo, uint32_t hi) {
  uint32_t rlo = (lo + 0x7FFFu + ((lo >> 16) & 1u)) >> 16;
  uint32_t rhi = (hi + 0x7FFFu + ((hi >> 16) & 1u)) >> 16;
  return (rhi << 16) | (rlo & 0xFFFFu);
}

__device__ __forceinline__ uint32_t sign2_bf16(uint32_t lo, uint32_t hi) {
  uint32_t slo = (lo & 0x7FFFFFFFu) ? (0x3F80u | ((lo >> 16) & 0x8000u)) : 0u;
  uint32_t shi = (hi & 0x7FFFFFFFu) ? (0x3F80u | ((hi >> 16) & 0x8000u)) : 0u;
  return (shi << 16) | slo;
}

__device__ __forceinline__ void gl16(const void* g, void* l) {
  __builtin_amdgcn_global_load_lds(
      (const __attribute__((address_space(1))) uint32_t*)g,
      (__attribute__((address_space(3))) uint32_t*)l,
      16, 0, 0);
}

// ---------- prep: f32 row-major -> bf16 FRAGMENT-TILE layout (R6-verified) ----------
// 16B chunk index = ((kt*(R/32)+mb)*4 + ks)*64 + sub*32 + r
// holds rows[mb*32+r], k = kt*64 + ks*16 + sub*8 .. +8.

__global__ void prep_frag(const float* __restrict__ x, uint4* __restrict__ xf, int Mx,
                          const float* __restrict__ w, uint4* __restrict__ wf, int Nw,
                          int K) {
  const int kpw = K >> 6;
  const long nxc = ((long)Mx * K) >> 3;
  const long nwc = ((long)Nw * K) >> 3;
  const long stride = (long)gridDim.x * blockDim.x;
  for (long c = (long)blockIdx.x * blockDim.x + threadIdx.x; c < nxc + nwc; c += stride) {
    const bool isX = (c < nxc);
    const float* src = isX ? x : w;
    uint4* dst = isX ? xf : wf;
    const int rows32 = (isX ? Mx : Nw) >> 5;
    const long cc = isX ? c : (c - nxc);

    const int t = (int)(cc & 63);
    const long wv = cc >> 6;
    const int band = (int)(wv / kpw);
    const int kg = (int)(wv % kpw);
    const int row = band * 8 + (t & 7);
    const int k8 = kg * 8 + (t >> 3);

    const int kt = k8 >> 3, ks = (k8 >> 1) & 3, sub = k8 & 1;
    const int mb = row >> 5, r = row & 31;
    const long out16 = ((long)(kt * rows32 + mb) * 4 + ks) * 64 + sub * 32 + r;

    const uint4* s = reinterpret_cast<const uint4*>(src + (long)row * K + k8 * 8);
    uint4 a = s[0], b = s[1];
    uint4 o;
    if (isX) {
      o.x = rn2_bf16(a.x, a.y); o.y = rn2_bf16(a.z, a.w);
      o.z = rn2_bf16(b.x, b.y); o.w = rn2_bf16(b.z, b.w);
    } else {
      o.x = sign2_bf16(a.x, a.y); o.y = sign2_bf16(a.z, a.w);
      o.z = sign2_bf16(b.x, b.y); o.w = sign2_bf16(b.z, b.w);
    }
    dst[out16] = o;
  }
}

// ---------- 256x256 GEMM, 32x32x16 MFMA, 2-phase read-ahead pipeline ----------
// R6 structure + 4-slot fragment rotation: frags read at phase s feed the MFMA
// at phase s+2 (slot s%4, rewritten s+4), so ds_read completion overlaps MFMA
// instead of serializing (R6 measured 1180 cyc/phase = 516 MFMA + 576 LDS in
// series; target max(576,516)).  Staging/VM0 schedule (audited):
//   tile u staged @4u-6,4u-5 -> VM0 @end 4u-3 (flight 2-3 phases > HBM lat;
//   exactly tile u's 8 loads outstanding) -> first read @4u-2.
//   STG overwrites a region whose last ds_read issued 1 phase earlier (same
//   gap as R4/R6, twice-verified race-free).

#define BARX()  asm volatile("s_barrier" ::: "memory")
#define VM0()   asm volatile("s_waitcnt vmcnt(0)" ::: "memory")
#define VMN8()  asm volatile("s_waitcnt vmcnt(8)" ::: "memory")

__global__ __launch_bounds__(512, 2) void gemm256(
    const uint16_t* __restrict__ Af,  // fragment-tile bf16
    const uint16_t* __restrict__ Bf,  // fragment-tile sign bf16
    const float* __restrict__ bias,   // [N]
    float* __restrict__ C,            // [M][N] f32
    int M, int N, int K) {
  __shared__ alignas(16) uint8_t L[131072];
  uint8_t* Lb = L;

  const int tid  = threadIdx.x;
  const int lane = tid & 63;
  const int w    = tid >> 6;
  const int wr   = w >> 2;        // 0..1 -> M rows [wr*128, +128)
  const int wc   = w & 3;         // 0..3 -> N cols [wc*64, +64)
  const int l31  = lane & 31;
  const int lhi  = lane >> 5;

  // bijective XCD swizzle (nwg % 8 == 0 guaranteed by launcher)
  const int nbx = N >> 8;
  const int nwg = nbx * (M >> 8);
  const int bid = blockIdx.x;
  const int swb = (bid & 7) * (nwg >> 3) + (bid >> 3);
  const size_t m0 = (size_t)(swb / nbx) << 8;
  const size_t n0 = (size_t)(swb % nbx) << 8;

  const int NT = K >> 6;                       // K64 tiles
  const size_t ktA = (size_t)(M >> 5) * 4096;  // bytes per kt plane (A)
  const size_t ktB = (size_t)(N >> 5) * 4096;  // bytes per kt plane (B)
  const char* Abase = (const char*)Af + (m0 >> 5) * 4096;
  const char* Bbase = (const char*)Bf + (n0 >> 5) * 4096;

  const int wB = w << 11;            // wave's 2KB slice of a 16KB half
  const int g0 = wB + lane * 16;
  const int g1 = g0 + 1024;

#define STG(LOFF, SRC) do { \
    gl16((SRC) + g0, Lb + (LOFF) + wB); \
    gl16((SRC) + g1, Lb + (LOFF) + wB + 1024); } while (0)

#define FRA32(d, i, q) (*reinterpret_cast<const bf16x8*>( \
    Lb + (d) * 65536 + wr * 16384 + (i) * 4096 + (q) * 1024 + lane * 16))
#define FRB32(d, j, q) (*reinterpret_cast<const bf16x8*>( \
    Lb + (d) * 65536 + 32768 + wc * 8192 + (j) * 4096 + (q) * 1024 + lane * 16))

#define RDA(DST, d, q) do { \
    _Pragma("unroll") \
    for (int i = 0; i < 4; ++i) DST[i] = FRA32(d, i, q); } while (0)
#define RDB(DST, d, q) do { \
    _Pragma("unroll") \
    for (int j = 0; j < 2; ++j) DST[j] = FRB32(d, j, q); } while (0)

  f32x16 acc[4][2] = {};

#define QM(A4, B2) do { \
    __builtin_amdgcn_s_setprio(1); \
    _Pragma("unroll") \
    for (int i = 0; i < 4; ++i) \
      _Pragma("unroll") \
      for (int j = 0; j < 2; ++j) \
        acc[i][j] = __builtin_amdgcn_mfma_f32_32x32x16_bf16( \
            A4[i], B2[j], acc[i][j], 0, 0, 0); \
    __builtin_amdgcn_s_setprio(0); } while (0)

  // ---- prologue: tile0 -> buf0, tile1 -> buf1; prime frag slots S0,S1 ----
  STG(0,      Abase);                 // t0 A lo
  STG(16384,  Abase + 16384);         // t0 A hi
  STG(32768,  Bbase);                 // t0 B lo
  STG(49152,  Bbase + 16384);         // t0 B hi
  STG(65536,  Abase + ktA);           // t1 A lo
  STG(81920,  Abase + ktA + 16384);   // t1 A hi
  STG(98304,  Bbase + ktB);           // t1 B lo
  STG(114688, Bbase + ktB + 16384);   // t1 B hi
  VMN8();   // drain tile0's 8 (tile1's 8 still in flight)
  BARX();

  bf16x8 S0a[4], S0b[2], S1a[4], S1b[2], S2a[4], S2b[2], S3a[4], S3b[2];
  RDA(S0a, 0, 0); RDB(S0b, 0, 0);   // t0 ks0 -> consumed ph0
  RDA(S1a, 0, 1); RDB(S1b, 0, 1);   // t0 ks1 -> consumed ph1

  const int T2 = K >> 7;  // iterations of 2 K-tiles
  for (int t = 0; t < T2; ++t) {
    const int u2 = 2 * t + 2, u3 = 2 * t + 3;
    const char* A2 = Abase + (size_t)(u2 < NT ? u2 : NT - 1) * ktA;
    const char* B2 = Bbase + (size_t)(u2 < NT ? u2 : NT - 1) * ktB;
    const char* A3 = Abase + (size_t)(u3 < NT ? u3 : NT - 1) * ktA;
    const char* B3 = Bbase + (size_t)(u3 < NT ? u3 : NT - 1) * ktB;

    // ph0: MFMA t(2t) ks0; read buf0 ks2 -> S2
    QM(S0a, S0b);
    RDA(S2a, 0, 2); RDB(S2b, 0, 2);
    BARX();

    // ph1: MFMA ks1; read buf0 ks3 -> S3; VM0 drains tile 2t+1
    QM(S1a, S1b);
    RDA(S3a, 0, 3); RDB(S3b, 0, 3);
    VM0();
    BARX();

    // ph2: MFMA ks2; read buf1 ks0 -> S0; stage A(2t+2) -> buf0
    QM(S2a, S2b);
    RDA(S0a, 1, 0); RDB(S0b, 1, 0);
    STG(0, A2);
    STG(16384, A2 + 16384);
    BARX();

    // ph3: MFMA ks3; read buf1 ks1 -> S1; stage B(2t+2) -> buf0
    QM(S3a, S3b);
    RDA(S1a, 1, 1); RDB(S1b, 1, 1);
    STG(32768, B2);
    STG(49152, B2 + 16384);
    BARX();

    // ph4: MFMA t(2t+1) ks0; read buf1 ks2 -> S2
    QM(S0a, S0b);
    RDA(S2a, 1, 2); RDB(S2b, 1, 2);
    BARX();

    // ph5: MFMA ks1; read buf1 ks3 -> S3; VM0 drains tile 2t+2
    QM(S1a, S1b);
    RDA(S3a, 1, 3); RDB(S3b, 1, 3);
    VM0();
    BARX();

    // ph6: MFMA ks2; read buf0 (tile 2t+2) ks0 -> S0; stage A(2t+3) -> buf1
    QM(S2a, S2b);
    RDA(S0a, 0, 0); RDB(S0b, 0, 0);
    STG(65536, A3);
    STG(81920, A3 + 16384);
    BARX();

    // ph7: MFMA ks3; read buf0 ks1 -> S1; stage B(2t+3) -> buf1
    QM(S3a, S3b);
    RDA(S1a, 0, 1); RDB(S1b, 0, 1);
    STG(98304, B3);
    STG(114688, B3 + 16384);
    BARX();
  }
  VM0();  // drain in-flight DMA before teardown

  // ---- epilogue: +bias, f32 store ----
  // C/D 32x32: col = lane&31, row = (reg&3) + 8*(reg>>2) + 4*(lane>>5)
#pragma unroll
  for (int i = 0; i < 4; ++i) {
#pragma unroll
    for (int j2 = 0; j2 < 2; ++j2) {
      const size_t col = n0 + wc * 64 + j2 * 32 + l31;
      const float bv = bias[col];
      const size_t rbase = m0 + wr * 128 + i * 32 + lhi * 4;
#pragma unroll
      for (int r = 0; r < 16; ++r) {
        const size_t row = rbase + (r & 3) + 8 * (r >> 2);
        C[row * N + col] = acc[i][j2][r] + bv;
      }
    }
  }
}

// ---------- naive f32 fallback (shape mismatch only) ----------
__global__ void gemm_naive(const float* __restrict__ x, const float* __restrict__ w,
                           const float* __restrict__ b, float* __restrict__ out,
                           int M, int N, int K) {
  int n = blockIdx.x * blockDim.x + threadIdx.x;
  int m = blockIdx.y;
  if (n >= N || m >= M) return;
  float acc = 0.f;
  for (int k = 0; k < K; ++k) {
    float wv = w[(size_t)n * K + k];
    float s = (wv > 0.f) ? 1.f : ((wv < 0.f) ? -1.f : 0.f);
    acc += x[(size_t)m * K + k] * s;
  }
  out[(size_t)m * N + n] = acc + b[n];
}

extern "C" void kernel_launch(void* const* d_in, const int* in_sizes, int n_in,
                              void* d_out, int out_size, void* d_ws, size_t ws_size,
                              hipStream_t stream) {
  const float* x = (const float*)d_in[0];
  const float* w = (const float*)d_in[1];
  const float* b = (const float*)d_in[2];
  float* out = (float*)d_out;

  const int N = in_sizes[2];
  const int K = in_sizes[1] / N;
  const int M = in_sizes[0] / K;

  const size_t need = ((size_t)M * K + (size_t)N * K) * sizeof(uint16_t);
  const bool big_ok = (M % 256 == 0) && (N % 256 == 0) && (K % 256 == 0) &&
                      (((M / 256) * (N / 256)) % 8 == 0) && (ws_size >= need);
  if (!big_ok) {
    hipLaunchKernelGGL(gemm_naive, dim3((N + 255) / 256, M), dim3(256), 0, stream,
                       x, w, b, out, M, N, K);
    return;
  }

  uint16_t* Xf = (uint16_t*)d_ws;
  uint16_t* Wf = Xf + (size_t)M * K;

  hipLaunchKernelGGL(prep_frag, dim3(2048), dim3(256), 0, stream,
                     x, (uint4*)Xf, M, w, (uint4*)Wf, N, K);

  hipLaunchKernelGGL(gemm256, dim3((M / 256) * (N / 256)), dim3(512), 0, stream,
                     Xf, Wf, b, out, M, N, K);
}

// Round 8
// 139.929 us; speedup vs baseline: 1.0429x; 1.0429x over previous
//
#include <hip/hip_runtime.h>
#include <hip/hip_bf16.h>
#include <stdint.h>

typedef __bf16 bf16x8 __attribute__((ext_vector_type(8)));
typedef float  f32x16 __attribute__((ext_vector_type(16)));

// ---------- helpers ----------

__device__ __forceinline__ uint32_t rn2_bf16(uint32_t lo, uint32_t hi) {
  uint32_t rlo = (lo + 0x7FFFu + ((lo >> 16) & 1u)) >> 16;
  uint32_t rhi = (hi + 0x7FFFu + ((hi >> 16) & 1u)) >> 16;
  return (rhi << 16) | (rlo & 0xFFFFu);
}

__device__ __forceinline__ uint32_t sign2_bf16(uint32_t lo, uint32_t hi) {
  uint32_t slo = (lo & 0x7FFFFFFFu) ? (0x3F80u | ((lo >> 16) & 0x8000u)) : 0u;
  uint32_t shi = (hi & 0x7FFFFFFFu) ? (0x3F80u | ((hi >> 16) & 0x8000u)) : 0u;
  return (shi << 16) | slo;
}

__device__ __forceinline__ void gl16(const void* g, void* l) {
  __builtin_amdgcn_global_load_lds(
      (const __attribute__((address_space(1))) uint32_t*)g,
      (__attribute__((address_space(3))) uint32_t*)l,
      16, 0, 0);
}

// ---------- prep: f32 row-major -> bf16 FRAGMENT-TILE layout (R6-verified) ----------
// 16B chunk index = ((kt*(R/32)+mb)*4 + ks)*64 + sub*32 + r
// holds rows[mb*32+r], k = kt*64 + ks*16 + sub*8 .. +8.

__global__ void prep_frag(const float* __restrict__ x, uint4* __restrict__ xf, int Mx,
                          const float* __restrict__ w, uint4* __restrict__ wf, int Nw,
                          int K) {
  const int kpw = K >> 6;
  const long nxc = ((long)Mx * K) >> 3;
  const long nwc = ((long)Nw * K) >> 3;
  const long stride = (long)gridDim.x * blockDim.x;
  for (long c = (long)blockIdx.x * blockDim.x + threadIdx.x; c < nxc + nwc; c += stride) {
    const bool isX = (c < nxc);
    const float* src = isX ? x : w;
    uint4* dst = isX ? xf : wf;
    const int rows32 = (isX ? Mx : Nw) >> 5;
    const long cc = isX ? c : (c - nxc);

    const int t = (int)(cc & 63);
    const long wv = cc >> 6;
    const int band = (int)(wv / kpw);
    const int kg = (int)(wv % kpw);
    const int row = band * 8 + (t & 7);
    const int k8 = kg * 8 + (t >> 3);

    const int kt = k8 >> 3, ks = (k8 >> 1) & 3, sub = k8 & 1;
    const int mb = row >> 5, r = row & 31;
    const long out16 = ((long)(kt * rows32 + mb) * 4 + ks) * 64 + sub * 32 + r;

    const uint4* s = reinterpret_cast<const uint4*>(src + (long)row * K + k8 * 8);
    uint4 a = s[0], b = s[1];
    uint4 o;
    if (isX) {
      o.x = rn2_bf16(a.x, a.y); o.y = rn2_bf16(a.z, a.w);
      o.z = rn2_bf16(b.x, b.y); o.w = rn2_bf16(b.z, b.w);
    } else {
      o.x = sign2_bf16(a.x, a.y); o.y = sign2_bf16(a.z, a.w);
      o.z = sign2_bf16(b.x, b.y); o.w = sign2_bf16(b.z, b.w);
    }
    dst[out16] = o;
  }
}

// ---------- 256x256 GEMM, 32x32x16 MFMA, interleaved DS||MFMA phases ----------
// R7 structure (4-slot rotation, 2-phase read-ahead, same STG/VM0 schedule,
// twice-audited race-free) with the phase body rewritten:
//  - NO setprio bracket (side-effecting SOPP = scheduler fence; it was
//    preventing ds_read/MFMA interleave -> pipes alternated: 516 cyc matrix +
//    576 cyc LDS in SERIES = measured 1186 cyc/phase, MfmaUtil 47%).
//  - ds_reads hand-interleaved 1:1 among the MFMAs in source order, pinned
//    with sched_group_barrier (T19): VMEM_READ first, then (DS_READ,MFMA)x6,
//    then MFMAx2. Target: phase ~= max(576,516) -> ~65% faster K-loop.

#define BARX()  asm volatile("s_barrier" ::: "memory")
#define VM0()   asm volatile("s_waitcnt vmcnt(0)" ::: "memory")
#define VMN8()  asm volatile("s_waitcnt vmcnt(8)" ::: "memory")
#define SGB(m, n) __builtin_amdgcn_sched_group_barrier((m), (n), 0)
#define MF(a, b, c) __builtin_amdgcn_mfma_f32_32x32x16_bf16((a), (b), (c), 0, 0, 0)

// (DS_READ,MFMA)x6 then MFMAx2
#define PIN6() do { \
    SGB(0x100,1); SGB(0x8,1); SGB(0x100,1); SGB(0x8,1); \
    SGB(0x100,1); SGB(0x8,1); SGB(0x100,1); SGB(0x8,1); \
    SGB(0x100,1); SGB(0x8,1); SGB(0x100,1); SGB(0x8,1); \
    SGB(0x8,2); } while (0)
// 4 global_load_lds first (STG phases)
#define PINV() SGB(0x20,4)

__global__ __launch_bounds__(512, 2) void gemm256(
    const uint16_t* __restrict__ Af,  // fragment-tile bf16
    const uint16_t* __restrict__ Bf,  // fragment-tile sign bf16
    const float* __restrict__ bias,   // [N]
    float* __restrict__ C,            // [M][N] f32
    int M, int N, int K) {
  __shared__ alignas(16) uint8_t L[131072];
  uint8_t* Lb = L;

  const int tid  = threadIdx.x;
  const int lane = tid & 63;
  const int w    = tid >> 6;
  const int wr   = w >> 2;        // 0..1 -> M rows [wr*128, +128)
  const int wc   = w & 3;         // 0..3 -> N cols [wc*64, +64)
  const int l31  = lane & 31;
  const int lhi  = lane >> 5;

  // bijective XCD swizzle (nwg % 8 == 0 guaranteed by launcher)
  const int nbx = N >> 8;
  const int nwg = nbx * (M >> 8);
  const int bid = blockIdx.x;
  const int swb = (bid & 7) * (nwg >> 3) + (bid >> 3);
  const size_t m0 = (size_t)(swb / nbx) << 8;
  const size_t n0 = (size_t)(swb % nbx) << 8;

  const int NT = K >> 6;                       // K64 tiles
  const size_t ktA = (size_t)(M >> 5) * 4096;  // bytes per kt plane (A)
  const size_t ktB = (size_t)(N >> 5) * 4096;  // bytes per kt plane (B)
  const char* Abase = (const char*)Af + (m0 >> 5) * 4096;
  const char* Bbase = (const char*)Bf + (n0 >> 5) * 4096;

  const int wB = w << 11;            // wave's 2KB slice of a 16KB half
  const int g0 = wB + lane * 16;
  const int g1 = g0 + 1024;

#define STG(LOFF, SRC) do { \
    gl16((SRC) + g0, Lb + (LOFF) + wB); \
    gl16((SRC) + g1, Lb + (LOFF) + wB + 1024); } while (0)

#define FRA32(d, i, q) (*reinterpret_cast<const bf16x8*>( \
    Lb + (d) * 65536 + wr * 16384 + (i) * 4096 + (q) * 1024 + lane * 16))
#define FRB32(d, j, q) (*reinterpret_cast<const bf16x8*>( \
    Lb + (d) * 65536 + 32768 + wc * 8192 + (j) * 4096 + (q) * 1024 + lane * 16))

  f32x16 acc[4][2] = {};

  // Interleaved phase: MFMA consumes (CAa,CAb); ds_reads refill (Ra,Rb) for
  // phase s+2. 1:1 weave so both pipes fill from every wave concurrently.
#define QMRD(CAa, CAb, Ra, Rb, d, q) do { \
    Ra[0] = FRA32(d, 0, q); \
    acc[0][0] = MF(CAa[0], CAb[0], acc[0][0]); \
    Ra[1] = FRA32(d, 1, q); \
    acc[0][1] = MF(CAa[0], CAb[1], acc[0][1]); \
    Ra[2] = FRA32(d, 2, q); \
    acc[1][0] = MF(CAa[1], CAb[0], acc[1][0]); \
    Ra[3] = FRA32(d, 3, q); \
    acc[1][1] = MF(CAa[1], CAb[1], acc[1][1]); \
    Rb[0] = FRB32(d, 0, q); \
    acc[2][0] = MF(CAa[2], CAb[0], acc[2][0]); \
    Rb[1] = FRB32(d, 1, q); \
    acc[2][1] = MF(CAa[2], CAb[1], acc[2][1]); \
    acc[3][0] = MF(CAa[3], CAb[0], acc[3][0]); \
    acc[3][1] = MF(CAa[3], CAb[1], acc[3][1]); \
  } while (0)

  // ---- prologue: tile0 -> buf0, tile1 -> buf1; prime frag slots S0,S1 ----
  STG(0,      Abase);                 // t0 A lo
  STG(16384,  Abase + 16384);         // t0 A hi
  STG(32768,  Bbase);                 // t0 B lo
  STG(49152,  Bbase + 16384);         // t0 B hi
  STG(65536,  Abase + ktA);           // t1 A lo
  STG(81920,  Abase + ktA + 16384);   // t1 A hi
  STG(98304,  Bbase + ktB);           // t1 B lo
  STG(114688, Bbase + ktB + 16384);   // t1 B hi
  VMN8();   // drain tile0's 8 (tile1's 8 still in flight)
  BARX();

  bf16x8 S0a[4], S0b[2], S1a[4], S1b[2], S2a[4], S2b[2], S3a[4], S3b[2];
#pragma unroll
  for (int i = 0; i < 4; ++i) S0a[i] = FRA32(0, i, 0);
#pragma unroll
  for (int j = 0; j < 2; ++j) S0b[j] = FRB32(0, j, 0);
#pragma unroll
  for (int i = 0; i < 4; ++i) S1a[i] = FRA32(0, i, 1);
#pragma unroll
  for (int j = 0; j < 2; ++j) S1b[j] = FRB32(0, j, 1);

  const int T2 = K >> 7;  // iterations of 2 K-tiles
  for (int t = 0; t < T2; ++t) {
    const int u2 = 2 * t + 2, u3 = 2 * t + 3;
    const char* A2 = Abase + (size_t)(u2 < NT ? u2 : NT - 1) * ktA;
    const char* B2 = Bbase + (size_t)(u2 < NT ? u2 : NT - 1) * ktB;
    const char* A3 = Abase + (size_t)(u3 < NT ? u3 : NT - 1) * ktA;
    const char* B3 = Bbase + (size_t)(u3 < NT ? u3 : NT - 1) * ktB;

    // ph0: MFMA t(2t) ks0; read buf0 ks2 -> S2
    QMRD(S0a, S0b, S2a, S2b, 0, 2);
    PIN6();
    BARX();

    // ph1: MFMA ks1; read buf0 ks3 -> S3; VM0 drains tile 2t+1
    QMRD(S1a, S1b, S3a, S3b, 0, 3);
    PIN6();
    VM0();
    BARX();

    // ph2: MFMA ks2; read buf1 ks0 -> S0; stage A(2t+2) -> buf0
    STG(0, A2);
    STG(16384, A2 + 16384);
    QMRD(S2a, S2b, S0a, S0b, 1, 0);
    PINV(); PIN6();
    BARX();

    // ph3: MFMA ks3; read buf1 ks1 -> S1; stage B(2t+2) -> buf0
    STG(32768, B2);
    STG(49152, B2 + 16384);
    QMRD(S3a, S3b, S1a, S1b, 1, 1);
    PINV(); PIN6();
    BARX();

    // ph4: MFMA t(2t+1) ks0; read buf1 ks2 -> S2
    QMRD(S0a, S0b, S2a, S2b, 1, 2);
    PIN6();
    BARX();

    // ph5: MFMA ks1; read buf1 ks3 -> S3; VM0 drains tile 2t+2
    QMRD(S1a, S1b, S3a, S3b, 1, 3);
    PIN6();
    VM0();
    BARX();

    // ph6: MFMA ks2; read buf0 (tile 2t+2) ks0 -> S0; stage A(2t+3) -> buf1
    STG(65536, A3);
    STG(81920, A3 + 16384);
    QMRD(S2a, S2b, S0a, S0b, 0, 0);
    PINV(); PIN6();
    BARX();

    // ph7: MFMA ks3; read buf0 ks1 -> S1; stage B(2t+3) -> buf1
    STG(98304, B3);
    STG(114688, B3 + 16384);
    QMRD(S3a, S3b, S1a, S1b, 0, 1);
    PINV(); PIN6();
    BARX();
  }
  VM0();  // drain in-flight DMA before teardown

  // ---- epilogue: +bias, f32 store ----
  // C/D 32x32: col = lane&31, row = (reg&3) + 8*(reg>>2) + 4*(lane>>5)
#pragma unroll
  for (int i = 0; i < 4; ++i) {
#pragma unroll
    for (int j2 = 0; j2 < 2; ++j2) {
      const size_t col = n0 + wc * 64 + j2 * 32 + l31;
      const float bv = bias[col];
      const size_t rbase = m0 + wr * 128 + i * 32 + lhi * 4;
#pragma unroll
      for (int r = 0; r < 16; ++r) {
        const size_t row = rbase + (r & 3) + 8 * (r >> 2);
        C[row * N + col] = acc[i][j2][r] + bv;
      }
    }
  }
}

// ---------- naive f32 fallback (shape mismatch only) ----------
__global__ void gemm_naive(const float* __restrict__ x, const float* __restrict__ w,
                           const float* __restrict__ b, float* __restrict__ out,
                           int M, int N, int K) {
  int n = blockIdx.x * blockDim.x + threadIdx.x;
  int m = blockIdx.y;
  if (n >= N || m >= M) return;
  float acc = 0.f;
  for (int k = 0; k < K; ++k) {
    float wv = w[(size_t)n * K + k];
    float s = (wv > 0.f) ? 1.f : ((wv < 0.f) ? -1.f : 0.f);
    acc += x[(size_t)m * K + k] * s;
  }
  out[(size_t)m * N + n] = acc + b[n];
}

extern "C" void kernel_launch(void* const* d_in, const int* in_sizes, int n_in,
                              void* d_out, int out_size, void* d_ws, size_t ws_size,
                              hipStream_t stream) {
  const float* x = (const float*)d_in[0];
  const float* w = (const float*)d_in[1];
  const float* b = (const float*)d_in[2];
  float* out = (float*)d_out;

  const int N = in_sizes[2];
  const int K = in_sizes[1] / N;
  const int M = in_sizes[0] / K;

  const size_t need = ((size_t)M * K + (size_t)N * K) * sizeof(uint16_t);
  const bool big_ok = (M % 256 == 0) && (N % 256 == 0) && (K % 256 == 0) &&
                      (((M / 256) * (N / 256)) % 8 == 0) && (ws_size >= need);
  if (!big_ok) {
    hipLaunchKernelGGL(gemm_naive, dim3((N + 255) / 256, M), dim3(256), 0, stream,
                       x, w, b, out, M, N, K);
    return;
  }

  uint16_t* Xf = (uint16_t*)d_ws;
  uint16_t* Wf = Xf + (size_t)M * K;

  hipLaunchKernelGGL(prep_frag, dim3(2048), dim3(256), 0, stream,
                     x, (uint4*)Xf, M, w, (uint4*)Wf, N, K);

  hipLaunchKernelGGL(gemm256, dim3((M / 256) * (N / 256)), dim3(512), 0, stream,
                     Xf, Wf, b, out, M, N, K);
}